// Round 19
// baseline (631.998 us; speedup 1.0000x reference)
//
#include <hip/hip_runtime.h>
#include <math.h>

typedef unsigned short ushort_t;
typedef __attribute__((ext_vector_type(8))) short short8;
typedef __attribute__((ext_vector_type(4))) float f32x4;

// ---------------- problem constants ----------------
constexpr int B = 16, S = 384, H = 768;
constexpr int BS = B * S;                                // 6144
constexpr long long PAIRS = (long long)S * (S + 1) / 2;  // 73920
constexpr float INV = 0.125f;                            // 1/sqrt(64)

__device__ __forceinline__ ushort_t f2bf(float f) {
  unsigned int u = __float_as_uint(f);
  u += 0x7FFF + ((u >> 16) & 1);       // round-to-nearest-even
  return (ushort_t)(u >> 16);
}
__device__ __forceinline__ float bf2f(ushort_t u) {
  return __uint_as_float(((unsigned int)u) << 16);
}

__device__ __forceinline__ void glds16(const ushort_t* g, ushort_t* l) {
  __builtin_amdgcn_global_load_lds(
      (const __attribute__((address_space(1))) unsigned int*)g,
      (__attribute__((address_space(3))) unsigned int*)l, 16, 0, 0);
}

// ---------------- bulk fp32 -> bf16 convert + fused setup (rope/bias) ----------------
// rgat_w conversion is EXCLUDED here (fused into the first CMODE6 dispatch).
constexpr int NJOBS = 13;
struct CvtJobs {
  const float* src[NJOBS];
  ushort_t* dst[NJOBS];
  int n_real[NJOBS];
  int n_tot[NJOBS];
  int blk_off[NJOBS + 1];
};
__global__ __launch_bounds__(256) void cvt_setup_kernel(
    CvtJobs J, int cvtBlocks, float* tab,
    const float* g_repq, const float* g_repk, const float* g_gtq, const float* g_gtk,
    const float* p_repq, const float* p_repk, const float* p_gtq, const float* p_gtk,
    const float* g_scq, const float* g_sck, const float* p_scq, const float* p_sck,
    float* bqkg, float* bqkp, float* bscg, float* bscp) {
  int blk = blockIdx.x;
  if (blk >= cvtBlocks) {                 // fused setup region (56 blocks)
    int b = blk - cvtBlocks;
    if (b < 48) {
      int s = b * 8 + (threadIdx.x >> 5);
      int i = threadIdx.x & 31;
      double ang = (double)s / pow(10000.0, (double)i / 32.0);
      tab[s * 64 + 2 * i]     = (float)cos(ang);
      tab[s * 64 + 2 * i + 1] = (float)sin(ang);
    } else {
      int t = (b - 48) * 256 + threadIdx.x;
      if (t < 1472)
        bqkg[t] = t < 672 ? g_repq[t] : t < 1344 ? g_repk[t - 672]
                : t < 1408 ? g_gtq[t - 1344] : g_gtk[t - 1408];
      if (t < 2048)
        bqkp[t] = t < 960 ? p_repq[t] : t < 1920 ? p_repk[t - 960]
                : t < 1984 ? p_gtq[t - 1920] : p_gtk[t - 1984];
      if (t < 1152) bscg[t] = t < 576 ? g_scq[t] : g_sck[t - 576];
      if (t < 768)  bscp[t] = t < 384 ? p_scq[t] : p_sck[t - 384];
    }
    return;
  }
  int j = 0;
  while (j < NJOBS - 1 && blk >= J.blk_off[j + 1]) ++j;
  int i4 = (blk - J.blk_off[j]) * 256 + threadIdx.x;
  if (i4 * 4 >= J.n_tot[j]) return;
  ushort4 o;
  if (i4 * 4 < J.n_real[j]) {
    float4 v = ((const float4*)J.src[j])[i4];
    o = make_ushort4(f2bf(v.x), f2bf(v.y), f2bf(v.z), f2bf(v.w));
  } else {
    o = make_ushort4(0, 0, 0, 0);
  }
  ((ushort4*)J.dst[j])[i4] = o;
}

// ---------------- GEMM argument pack ----------------
struct GemmArgs {
  const ushort_t* A; const ushort_t* W; const float* bias; void* Cv;
  ushort_t* pl; ushort_t* qd; ushort_t* kd; int cbase, nsplit;
  int N, K, lda, ldw, ldc; float alpha; int nh;
  long long sAb, sAh, sWb, sWh, sCb, sCh;
  const float* mask; const float* tab; int biasN;
  int nx, ny, nz;
};

// ---------------- MFMA NT GEMM body, 2-phase pipelined ----------------
// CMODE semantics identical to prior rounds (2/3/5/6/8). XCD swizzle +
// GROUP_M=8 banding applied from the linear block id `flat`. SH: 17408 ushorts
// provided by the wrapper kernel (single allocation for dual dispatch).
template <int ACT, int CMODE>
__device__ void gemm_body(const GemmArgs g, int flat, ushort_t* SH) {
  const int nx = g.nx, ny = g.ny;
  int bx, by, bz;
  {
    const int nwg = nx * ny * g.nz;
    int l = (flat & 7) * (nwg >> 3) + (flat >> 3);
    const int pz = l / (nx * ny);
    int l2 = l - pz * (nx * ny);
    const int GM = 8;
    const int band = l2 / (GM * nx);
    const int rem = l2 - band * (GM * nx);
    const int gm = (ny - band * GM < GM) ? (ny - band * GM) : GM;
    bx = rem / gm;
    by = band * GM + (rem - bx * gm);
    bz = pz;
  }
  const int zb = bz / g.nh, zh = bz - zb * g.nh;
  const ushort_t* A = g.A + zb * g.sAb + zh * g.sAh;
  const ushort_t* W = g.W + zb * g.sWb + zh * g.sWh;
  const int t = threadIdx.x;
  int m0, n0;
  if (CMODE == 3 || CMODE == 8) {   // upper-pair map: bx in [0,6)
    const int ti = (bx < 3) ? 0 : (bx < 5 ? 1 : 2);
    const int tj = (bx < 3) ? bx : (bx < 5 ? bx - 2 : 2);
    m0 = ti * 128; n0 = tj * 128;
  } else {
    m0 = by * 128; n0 = bx * 128;
  }
  const int lane = t & 63, wid = t >> 6;
  const int wr = wid >> 1, wc = wid & 1;
  const int lrow = lane & 15, lk = lane >> 4;
  const int srow = t >> 2, sch = (t & 3) * 8;
  const int lda = g.lda, ldw = g.ldw, ldc = g.ldc;
  const ushort_t* Ag = A + (size_t)(m0 + srow) * lda + sch;
  const ushort_t* Wg = W + (size_t)(n0 + srow) * ldw + sch;
  const size_t a64 = (size_t)64 * lda, w64 = (size_t)64 * ldw;

  f32x4 acc[4][4];
#pragma unroll
  for (int i = 0; i < 4; ++i)
#pragma unroll
    for (int j = 0; j < 4; ++j) acc[i][j] = (f32x4){0.f, 0.f, 0.f, 0.f};

  auto stage = [&](int k0, int buf) {
    const int ao = buf * 4096, bo = 8192 + buf * 4096;
    glds16(Ag + k0, &SH[ao + t * 8]);
    glds16(Ag + k0 + a64, &SH[ao + 2048 + t * 8]);
    glds16(Wg + k0, &SH[bo + t * 8]);
    glds16(Wg + k0 + w64, &SH[bo + 2048 + t * 8]);
  };

  const int nk = g.K >> 5;
  stage(0, 0);
  for (int s = 0; s < nk; ++s) {
    __syncthreads();                       // stage(s) visible; prev reads done
    if (s + 1 < nk) stage((s + 1) << 5, (s + 1) & 1);
    const int ao = (s & 1) * 4096, bo = 8192 + (s & 1) * 4096;
    short8 av[4], bv[4];
#pragma unroll
    for (int i = 0; i < 4; ++i) {
      av[i] = *(const short8*)&SH[ao + (wr * 64 + i * 16 + lrow) * 32 + lk * 8];
      bv[i] = *(const short8*)&SH[bo + (wc * 64 + i * 16 + lrow) * 32 + lk * 8];
    }
#pragma unroll
    for (int i = 0; i < 4; ++i)
#pragma unroll
      for (int j = 0; j < 4; ++j)
        acc[i][j] = __builtin_amdgcn_mfma_f32_16x16x32_bf16(av[i], bv[j],
                                                            acc[i][j], 0, 0, 0);
  }

  if (CMODE == 2) {
    // LDS-staged transposed epilogue: tile [n_local][s_local], stride 136
    __syncthreads();
    const int bb = m0 / S;
    ushort_t* Cb = (ushort_t*)g.Cv + (size_t)bb * g.sCb;
    const int s_base = m0 - bb * S;
#pragma unroll
    for (int i = 0; i < 4; ++i) {
      const int sl = wr * 64 + i * 16 + lk * 4;
#pragma unroll
      for (int j = 0; j < 4; ++j) {
        const int nl = wc * 64 + j * 16 + lrow;
        ushort4 o = make_ushort4(f2bf(acc[i][j][0]), f2bf(acc[i][j][1]),
                                 f2bf(acc[i][j][2]), f2bf(acc[i][j][3]));
        *(ushort4*)&SH[nl * 136 + sl] = o;
      }
    }
    __syncthreads();
#pragma unroll
    for (int it = 0; it < 8; ++it) {
      const int row = it * 16 + wid * 4 + lk;
      ushort_t* dst = Cb + (size_t)(n0 + row) * ldc + s_base + lrow * 8;
      *(short8*)dst = *(const short8*)&SH[row * 136 + lrow * 8];
    }
  } else if (CMODE == 3) {
    ushort_t* plc = g.pl + ((size_t)(g.cbase + zh) * B + zb) * PAIRS;
#pragma unroll
    for (int j = 0; j < 4; ++j) {
      const int n = n0 + wc * 64 + j * 16 + lrow;
#pragma unroll
      for (int i = 0; i < 4; ++i) {
#pragma unroll
        for (int e = 0; e < 4; ++e) {
          const int m = m0 + wr * 64 + i * 16 + lk * 4 + e;
          if (n >= m) {
            long long p = (long long)m * S - (long long)m * (m - 1) / 2 + (n - m);
            float v = g.alpha * acc[i][j][e];
            if (ACT == 1) v = fmaxf(v, 0.f);
            plc[p] = f2bf(v);
          }
        }
      }
    }
  } else if (CMODE == 5) {
    // bias -> rope(pair via shfl_xor 1) -> mask -> bf16 to qd (+zh*sCh)
    ushort_t* Cq = g.qd + (size_t)zh * g.sCh;
    const float* bz2 = g.bias + (size_t)zh * g.biasN;
#pragma unroll
    for (int j = 0; j < 4; ++j) {
      const int n = n0 + wc * 64 + j * 16 + lrow;
      const float vb = (n < g.N) ? bz2[n] : 0.f;
      const int d = n & 63;
      const int ti2 = d & ~1;
#pragma unroll
      for (int i = 0; i < 4; ++i) {
#pragma unroll
        for (int e = 0; e < 4; ++e) {
          const int m = m0 + wr * 64 + i * 16 + lk * 4 + e;
          const int s = m % S;
          float v = (n < g.N) ? (acc[i][j][e] + vb) : 0.f;
          float pv = __shfl_xor(v, 1);
          float c = g.tab[s * 64 + ti2], sn = g.tab[s * 64 + ti2 + 1];
          float o = (d & 1) ? (v * c + pv * sn) : (v * c - pv * sn);
          o *= g.mask[m];
          if (n < g.N) Cq[(size_t)m * ldc + n] = f2bf(o);
        }
      }
    }
  } else if (CMODE == 6) {
    // split epilogue: rep (relu bf16) for n<nsplit, gt rope for nsplit<=n<N
    ushort_t* Cu = (ushort_t*)g.Cv;
#pragma unroll
    for (int j = 0; j < 4; ++j) {
      const int n = n0 + wc * 64 + j * 16 + lrow;
      const float vb = (n < g.N) ? g.bias[n] : 0.f;
#pragma unroll
      for (int i = 0; i < 4; ++i) {
#pragma unroll
        for (int e = 0; e < 4; ++e) {
          const int m = m0 + wr * 64 + i * 16 + lk * 4 + e;
          float v = (n < g.N) ? (acc[i][j][e] + vb) : 0.f;
          float pv = __shfl_xor(v, 1);
          if (n < g.nsplit) {
            Cu[(size_t)m * ldc + n] = f2bf(fmaxf(v, 0.f));
          } else if (n < g.N) {
            const int d = n - g.nsplit;
            const int dd = d & 63;
            const int ti2 = dd & ~1;
            const int s = m % S;
            float c = g.tab[s * 64 + ti2], sn = g.tab[s * 64 + ti2 + 1];
            float o = (dd & 1) ? (v * c + pv * sn) : (v * c - pv * sn);
            o *= g.mask[m];
            if (d < 64) g.qd[(size_t)m * 64 + dd] = f2bf(o);
            else        g.kd[(size_t)m * 64 + dd] = f2bf(o);
          }
        }
      }
    }
  } else if (CMODE == 8) {
    // symmetric score: att upper tile + planes, then LDS-mirrored tile
    ushort_t* Cu = (ushort_t*)g.Cv + zb * g.sCb + zh * g.sCh;
    ushort_t* plc = g.pl + ((size_t)(g.cbase + zh) * B + zb) * PAIRS;
    const bool diag = (m0 == n0);
#pragma unroll
    for (int j = 0; j < 4; ++j) {
      const int n = n0 + wc * 64 + j * 16 + lrow;
#pragma unroll
      for (int i = 0; i < 4; ++i) {
#pragma unroll
        for (int e = 0; e < 4; ++e) {
          const int m = m0 + wr * 64 + i * 16 + lk * 4 + e;
          float v = g.alpha * acc[i][j][e];
          ushort_t vb = f2bf(v);
          if (!diag || n >= m) Cu[(size_t)m * ldc + n] = vb;
          if (zh < 8 && n >= m) {
            long long p = (long long)m * S - (long long)m * (m - 1) / 2 + (n - m);
            plc[p] = vb;
          }
        }
      }
    }
    __syncthreads();   // all waves done reading SH (K-loop)
#pragma unroll
    for (int i = 0; i < 4; ++i) {
      const int sl = wr * 64 + i * 16 + lk * 4;
#pragma unroll
      for (int j = 0; j < 4; ++j) {
        const int nl = wc * 64 + j * 16 + lrow;
        ushort4 o4 = make_ushort4(f2bf(g.alpha * acc[i][j][0]),
                                  f2bf(g.alpha * acc[i][j][1]),
                                  f2bf(g.alpha * acc[i][j][2]),
                                  f2bf(g.alpha * acc[i][j][3]));
        *(ushort4*)&SH[nl * 136 + sl] = o4;
      }
    }
    __syncthreads();
#pragma unroll
    for (int it = 0; it < 8; ++it) {
      const int rowN = it * 16 + wid * 4 + lk;   // n-local 0..127
      const int colM = lrow * 8;                 // m-local chunk
      if (!diag) {
        *(short8*)&Cu[(size_t)(n0 + rowN) * ldc + m0 + colM] =
            *(const short8*)&SH[rowN * 136 + colM];
      } else {
#pragma unroll
        for (int q = 0; q < 8; ++q)
          if (rowN > colM + q)
            Cu[(size_t)(n0 + rowN) * ldc + m0 + colM + q] =
                SH[rowN * 136 + colM + q];
      }
    }
  }
}

template <int ACT, int CMODE>
__global__ __launch_bounds__(256) void gemm_one(GemmArgs g) {
  __shared__ __align__(16) ushort_t SH[17408];
  gemm_body<ACT, CMODE>(g, blockIdx.x + g.nx * (blockIdx.y + g.ny * blockIdx.z), SH);
}

// dual dispatch: two independent GEMM configs in one launch (1-D grid).
template <int ACTA, int CMA, int ACTB, int CMB>
__global__ __launch_bounds__(256) void gemm_dual(GemmArgs a, GemmArgs b, int nA) {
  __shared__ __align__(16) ushort_t SH[17408];
  int f = blockIdx.x;
  if (f < nA) gemm_body<ACTA, CMA>(a, f, SH);
  else        gemm_body<ACTB, CMB>(b, f - nA, SH);
}

// GEMM + fused fp32->bf16 conversion of an independent array (blocks >= nA).
template <int ACT, int CMODE>
__global__ __launch_bounds__(256) void gemm_cvt(
    GemmArgs a, int nA, const float* __restrict__ csrc,
    ushort_t* __restrict__ cdst, int cn) {
  __shared__ __align__(16) ushort_t SH[17408];
  int f = blockIdx.x;
  if (f < nA) {
    gemm_body<ACT, CMODE>(a, f, SH);
  } else {
    int i4 = (f - nA) * 256 + threadIdx.x;
    if (i4 * 4 < cn) {
      float4 v = ((const float4*)csrc)[i4];
      ((ushort4*)cdst)[i4] =
          make_ushort4(f2bf(v.x), f2bf(v.y), f2bf(v.z), f2bf(v.w));
    }
  }
}

// ---------------- adj bmm: Q[rg] = sum_{r in group} relu(adj[b,r] @ hr[b,r]) ----------------
// 5 relation groups (2,2,2,2,1) -> grid (6,3,B*5)=1440 blocks. bf16 partials.
__global__ __launch_bounds__(256) void adj_bmm_kernel(
    const ushort_t* __restrict__ adjb, const ushort_t* __restrict__ hrt,
    ushort_t* __restrict__ Q0, ushort_t* __restrict__ Q1,
    ushort_t* __restrict__ Q2, ushort_t* __restrict__ Q3,
    ushort_t* __restrict__ Q4) {
  __shared__ __align__(16) ushort_t As[2][128 * 32];
  __shared__ __align__(16) ushort_t Bs[2][128 * 32];
  int bx = blockIdx.x, by = blockIdx.y, bz = blockIdx.z;
  {   // XCD swizzle (nwg = 1440, %8==0)
    int nx = gridDim.x, ny = gridDim.y;
    int nwg = nx * ny * gridDim.z;
    int flat = bx + nx * (by + ny * bz);
    int l = (flat & 7) * (nwg >> 3) + (flat >> 3);
    bx = l % nx; l /= nx; by = l % ny; bz = l / ny;
  }
  const int b = bz / 5, rg = bz - b * 5;
  ushort_t* Q = (rg == 0) ? Q0 : (rg == 1) ? Q1 : (rg == 2) ? Q2
              : (rg == 3) ? Q3 : Q4;
  const int rel0 = (rg < 4) ? rg * 2 : 8;
  const int nsteps = (rg < 4) ? 24 : 12;   // 12 K-steps per relation
  const int t = threadIdx.x;
  const int m0 = by * 128, n0 = bx * 128;
  const int lane = t & 63, wid = t >> 6;
  const int wr = wid >> 1, wc = wid & 1;
  const int lrow = lane & 15, lk = lane >> 4;
  const int srow = t >> 2, sch = (t & 3) * 8;

  const ushort_t* adjA =
      adjb + ((size_t)(b * 9 + rel0) * S + m0 + srow) * S + sch;
  const ushort_t* hrA =
      hrt + ((size_t)(b * 9 + rel0) * H + n0 + srow) * S + sch;

  float mac[4][4][4];
#pragma unroll
  for (int i = 0; i < 4; ++i)
#pragma unroll
    for (int j = 0; j < 4; ++j)
#pragma unroll
      for (int e = 0; e < 4; ++e) mac[i][j][e] = 0.f;

  f32x4 acc[4][4];
#pragma unroll
  for (int i = 0; i < 4; ++i)
#pragma unroll
    for (int j = 0; j < 4; ++j) acc[i][j] = (f32x4){0.f, 0.f, 0.f, 0.f};

  auto stage = [&](int s, int buf) {
    const int rr = s / 12;
    const int k0 = (s - rr * 12) * 32;
    const ushort_t* Ag = adjA + (size_t)rr * S * S + k0;
    const ushort_t* Wg = hrA + (size_t)rr * H * S + k0;
    glds16(Ag, &As[buf][t * 8]);
    glds16(Ag + 64 * S, &As[buf][2048 + t * 8]);
    glds16(Wg, &Bs[buf][t * 8]);
    glds16(Wg + 64 * S, &Bs[buf][2048 + t * 8]);
  };

  stage(0, 0);
  for (int s = 0; s < nsteps; ++s) {
    __syncthreads();
    if (s + 1 < nsteps) stage(s + 1, (s + 1) & 1);
    const int buf = s & 1;
    short8 av[4], bv[4];
#pragma unroll
    for (int i = 0; i < 4; ++i) {
      av[i] = *(const short8*)&As[buf][(wr * 64 + i * 16 + lrow) * 32 + lk * 8];
      bv[i] = *(const short8*)&Bs[buf][(wc * 64 + i * 16 + lrow) * 32 + lk * 8];
    }
#pragma unroll
    for (int i = 0; i < 4; ++i)
#pragma unroll
      for (int j = 0; j < 4; ++j)
        acc[i][j] = __builtin_amdgcn_mfma_f32_16x16x32_bf16(av[i], bv[j],
                                                            acc[i][j], 0, 0, 0);
    if ((s % 12) == 11) {   // relation boundary: relu-accumulate, reset
#pragma unroll
      for (int i = 0; i < 4; ++i)
#pragma unroll
        for (int j = 0; j < 4; ++j) {
#pragma unroll
          for (int e = 0; e < 4; ++e)
            mac[i][j][e] += fmaxf(acc[i][j][e], 0.f);
          acc[i][j] = (f32x4){0.f, 0.f, 0.f, 0.f};
        }
    }
  }

#pragma unroll
  for (int i = 0; i < 4; ++i)
#pragma unroll
    for (int j = 0; j < 4; ++j)
#pragma unroll
      for (int e = 0; e < 4; ++e) {
        const int m = m0 + wr * 64 + i * 16 + lk * 4 + e;
        const int n = n0 + wc * 64 + j * 16 + lrow;
        Q[((size_t)b * S + m) * H + n] = f2bf(mac[i][j][e]);
      }
}

// ---------------- softmax row + (att!=0) mask: bf16 in -> bf16 adj ----------------
__global__ __launch_bounds__(128) void softmax_mask_kernel(
    const ushort_t* __restrict__ Mt, ushort_t* __restrict__ adjb) {
  __shared__ float red[128];
  int row = blockIdx.x;                // B*9*S rows
  const ushort_t* r = Mt + (size_t)row * S;
  ushort_t* o = adjb + (size_t)row * S;
  int t = threadIdx.x;
  const bool act = t < 96;             // 96 x ushort4 = 384 elems
  float v[4];
  float mx = -INFINITY;
  if (act) {
    ushort4 u = ((const ushort4*)r)[t];
    v[0] = bf2f(u.x); v[1] = bf2f(u.y); v[2] = bf2f(u.z); v[3] = bf2f(u.w);
    mx = fmaxf(fmaxf(v[0], v[1]), fmaxf(v[2], v[3]));
  }
  red[t] = mx; __syncthreads();
  for (int off2 = 64; off2 > 0; off2 >>= 1) {
    if (t < off2) red[t] = fmaxf(red[t], red[t + off2]);
    __syncthreads();
  }
  mx = red[0]; __syncthreads();
  float e4[4], s = 0.f;
  if (act) {
#pragma unroll
    for (int q = 0; q < 4; ++q) { e4[q] = expf(v[q] - mx); s += e4[q]; }
  }
  red[t] = s; __syncthreads();
  for (int off2 = 64; off2 > 0; off2 >>= 1) {
    if (t < off2) red[t] += red[t + off2];
    __syncthreads();
  }
  float invs = 1.f / red[0];
  if (act) {
    ushort4 ou;
    ou.x = f2bf((v[0] != 0.f) ? e4[0] * invs : 0.f);
    ou.y = f2bf((v[1] != 0.f) ? e4[1] * invs : 0.f);
    ou.z = f2bf((v[2] != 0.f) ? e4[2] * invs : 0.f);
    ou.w = f2bf((v[3] != 0.f) ? e4[3] * invs : 0.f);
    ((ushort4*)o)[t] = ou;
  }
}

// ---------------- RGAT finalize: feat = LN(sum(Q0..Q4)/9) -> bf16 into inp[:,768:1536],
// and copy xb -> inp[:,0:768] (fused). No partial aliases inp -> no hazard.
__global__ __launch_bounds__(256) void ln_finalize_kernel(
    const ushort_t* __restrict__ Q0, const ushort_t* __restrict__ Q1,
    const ushort_t* __restrict__ Q2, const ushort_t* __restrict__ Q3,
    const ushort_t* __restrict__ Q4, const ushort_t* __restrict__ xb,
    ushort_t* __restrict__ inp) {
  __shared__ float red[256];
  int row = blockIdx.x;
  const size_t base = (size_t)row * H;
  ushort_t* xrow = inp + (size_t)row * (2 * H);
  ushort_t* fb = xrow + H;
  int t = threadIdx.x;
  float v[3];
  float s = 0.f;
#pragma unroll
  for (int q = 0; q < 3; ++q) {
    size_t ix = base + t + q * 256;
    v[q] = (bf2f(Q0[ix]) + bf2f(Q1[ix]) + bf2f(Q2[ix]) + bf2f(Q3[ix]) +
            bf2f(Q4[ix])) / 9.0f;          // terms >= 0, relu is no-op
    s += v[q];
  }
  red[t] = s; __syncthreads();
#pragma unroll
  for (int q = 0; q < 3; ++q)
    xrow[t + q * 256] = xb[base + t + q * 256];
  for (int off2 = 128; off2 > 0; off2 >>= 1) {
    if (t < off2) red[t] += red[t + off2];
    __syncthreads();
  }
  float mean = red[0] / (float)H; __syncthreads();
  float s2 = 0.f;
#pragma unroll
  for (int q = 0; q < 3; ++q) { float d = v[q] - mean; s2 += d * d; }
  red[t] = s2; __syncthreads();
  for (int off2 = 128; off2 > 0; off2 >>= 1) {
    if (t < off2) red[t] += red[t + off2];
    __syncthreads();
  }
  float var = red[0] / (float)H;
  float rs = rsqrtf(var + 1e-5f);
#pragma unroll
  for (int q = 0; q < 3; ++q)
    fb[t + q * 256] = f2bf((v[q] - mean) * rs);
}

// ---------------- final gather: 16 bf16 planes -> out[b,p,16] fp32 ----------------
__global__ __launch_bounds__(256) void gather16_kernel(
    const ushort_t* __restrict__ plA, const ushort_t* __restrict__ plB,
    float* __restrict__ out) {
  int idx = blockIdx.x * 256 + threadIdx.x;          // b*PAIRS + p
  if (idx >= (int)(B * PAIRS)) return;
  const size_t PLN = (size_t)B * PAIRS;
  float v[16];
#pragma unroll
  for (int ch = 0; ch < 7; ++ch)  v[ch] = bf2f(plA[(size_t)ch * PLN + idx]);
#pragma unroll
  for (int ch = 7; ch < 16; ++ch) v[ch] = bf2f(plB[(size_t)(ch - 7) * PLN + idx]);
  float4* dst = (float4*)(out + (size_t)idx * 16);
#pragma unroll
  for (int q = 0; q < 4; ++q)
    dst[q] = make_float4(v[4 * q], v[4 * q + 1], v[4 * q + 2], v[4 * q + 3]);
}

// ---------------- launch ----------------
extern "C" void kernel_launch(void* const* d_in, const int* in_sizes, int n_in,
                              void* d_out, int out_size, void* d_ws, size_t ws_size,
                              hipStream_t stream) {
  (void)in_sizes; (void)n_in; (void)out_size; (void)ws_size;
  const float* x          = (const float*)d_in[0];
  const float* mask       = (const float*)d_in[1];
  const float* wq4gt_w    = (const float*)d_in[2];
  const float* wq4gt_b    = (const float*)d_in[3];
  const float* wk4gt_w    = (const float*)d_in[4];
  const float* wk4gt_b    = (const float*)d_in[5];
  const float* wq4g_rep_w = (const float*)d_in[6];
  const float* wq4g_rep_b = (const float*)d_in[7];
  const float* wq4g_sc_w  = (const float*)d_in[8];
  const float* wq4g_sc_b  = (const float*)d_in[9];
  const float* wk4g_rep_w = (const float*)d_in[10];
  const float* wk4g_rep_b = (const float*)d_in[11];
  const float* wk4g_sc_w  = (const float*)d_in[12];
  const float* wk4g_sc_b  = (const float*)d_in[13];
  const float* rgat_w     = (const float*)d_in[14];
  const float* wq4t_w     = (const float*)d_in[15];
  const float* wq4t_b     = (const float*)d_in[16];
  const float* wk4t_w     = (const float*)d_in[17];
  const float* wk4t_b     = (const float*)d_in[18];
  const float* wq_rep_w   = (const float*)d_in[19];
  const float* wq_rep_b   = (const float*)d_in[20];
  const float* wq_sc_w    = (const float*)d_in[21];
  const float* wq_sc_b    = (const float*)d_in[22];
  const float* wk_rep_w   = (const float*)d_in[23];
  const float* wk_rep_b   = (const float*)d_in[24];
  const float* wk_sc_w    = (const float*)d_in[25];
  const float* wk_sc_b    = (const float*)d_in[26];
  float* out = (float*)d_out;

  // ---- workspace carve-up (256B aligned); total ~267 MB ----
  char* wsb = (char*)d_ws;
  size_t off = 0;
  auto af = [&](size_t n) { float* p = (float*)(wsb + off);
                            off += ((n * 4 + 255) & ~(size_t)255); return p; };
  auto au = [&](size_t n) { ushort_t* p = (ushort_t*)(wsb + off);
                            off += ((n * 2 + 255) & ~(size_t)255); return p; };

  float* t_rope = af(24576);
  float* t_scg  = af((size_t)B * 9 * S * S);      // bf16 hr_t region
  float* t_acc  = af((size_t)BS * H);             // Q0+Q1 (bf16 partials)
  ushort_t* xb    = au((size_t)BS * H);
  ushort_t* inpb  = au((size_t)BS * 2 * H);       // scg_u head / [xb|feat] bf16
  ushort_t* repb  = au((size_t)BS * 1920);        // scg_u tail / Q2+Q3 / rep out
  ushort_t* qb    = au((size_t)BS * 576);         // kb must follow adjacently
  ushort_t* kb    = au((size_t)BS * 576);         // qb+kb host Q4 during RGAT
  ushort_t* adjb  = au((size_t)B * 9 * S * S);    // gtq/gtk carve pre-softmax
  ushort_t* plB   = au((size_t)9 * B * PAIRS);    // planes ch 7..15
  ushort_t* wqkg  = au(1179648);     // [1536,768]: repq|repk|gtq|gtk|pad
  ushort_t* wqkp  = au(3145728);     // [2048,1536]: repq|repk|gtq|gtk
  ushort_t* wq4g_scb = au(430080);   // [640,672] (576 real) -- adjacent pair
  ushort_t* wk4g_scb = au(430080);
  ushort_t* wq_scb   = au(368640);   // [384,960] -- adjacent pair
  ushort_t* wk_scb   = au(368640);
  ushort_t* rgatb    = au(10616832); // dead after last hr GEMM -> plA alias
  float* bqkg = af(1472);
  float* bqkp = af(2048);
  float* bscg = af(1152);
  float* bscp = af(768);

  // scg_u relocated to inpb+repb (exactly B*9*S*S ushorts, contiguous, both
  // dead in the score->softmax window) so score can run CONCURRENT with hr l=0.
  ushort_t* scg_u = inpb;
  ushort_t* hr_t  = (ushort_t*)t_scg;        // bf16 [B,9,H,S]
  ushort_t* plA   = rgatb;                   // planes ch 0..6 (16.6MB <= 21.2MB)
  ushort_t* gtq   = adjb;                    // gt q/k: adjb dead until softmax
  ushort_t* gtk   = adjb + (size_t)BS * 64;  // (graph) / dead after RGAT (pred)
  // bf16 RGAT partials (each BS*H ushorts = 9.44 MB), regions dead in RGAT:
  ushort_t* Q0 = (ushort_t*)t_acc;
  ushort_t* Q1 = Q0 + (size_t)BS * H;
  ushort_t* Q2 = repb;
  ushort_t* Q3 = Q2 + (size_t)BS * H;
  ushort_t* Q4 = qb;                         // qb+kb contiguous

  // ---- bulk convert weights (+x, NOT rgat_w) to bf16 + fused setup ----
  {
    CvtJobs J;
    const float* srcs[NJOBS] = {wq4g_rep_w, wk4g_rep_w, wq4gt_w, wk4gt_w,
                                wq_rep_w, wk_rep_w, wq4t_w, wk4t_w,
                                wq4g_sc_w, wk4g_sc_w, wq_sc_w, wk_sc_w, x};
    ushort_t* dsts[NJOBS] = {wqkg, wqkg + 516096, wqkg + 1032192, wqkg + 1081344,
                             wqkp, wqkp + 1474560, wqkp + 2949120, wqkp + 3047424,
                             wq4g_scb, wk4g_scb, wq_scb, wk_scb, xb};
    int nreal[NJOBS] = {516096, 516096, 49152, 49152,
                        1474560, 1474560, 98304, 98304,
                        387072, 387072, 368640, 368640, 4718592};
    int ntot[NJOBS]  = {516096, 516096, 49152, 98304,
                        1474560, 1474560, 98304, 98304,
                        430080, 430080, 368640, 368640, 4718592};
    int acc_blk = 0;
    for (int j = 0; j < NJOBS; ++j) {
      J.src[j] = srcs[j]; J.dst[j] = dsts[j];
      J.n_real[j] = nreal[j]; J.n_tot[j] = ntot[j];
      J.blk_off[j] = acc_blk;
      acc_blk += (ntot[j] + 1023) / 1024;
    }
    J.blk_off[NJOBS] = acc_blk;
    cvt_setup_kernel<<<acc_blk + 56, 256, 0, stream>>>(
        J, acc_blk, t_rope,
        wq4g_rep_b, wk4g_rep_b, wq4gt_b, wk4gt_b,
        wq_rep_b, wk_rep_b, wq4t_b, wk4t_b,
        wq4g_sc_b, wk4g_sc_b, wq_sc_b, wk_sc_b,
        bqkg, bqkp, bscg, bscp);
  }

  auto GA = [](const ushort_t* A, const ushort_t* W, const float* bias, void* Cv,
               ushort_t* pl, ushort_t* qd, ushort_t* kd, int cbase, int nsplit,
               int N, int K, int lda, int ldw, int ldc, float alpha, int nh,
               long long sAb, long long sAh, long long sWb, long long sWh,
               long long sCb, long long sCh,
               const float* mask, const float* tab, int biasN,
               int nx, int ny, int nz) {
    GemmArgs g{A, W, bias, Cv, pl, qd, kd, cbase, nsplit,
               N, K, lda, ldw, ldc, alpha, nh,
               sAb, sAh, sWb, sWh, sCb, sCh, mask, tab, biasN, nx, ny, nz};
    return g;
  };

  // ---- graph layer: merged rep-MLP + gt-proj, FUSED with rgat_w conversion ----
  // rgat cvt (10368 blocks) hides under the 576-block GEMM; completes before
  // the hr dual below by stream order.
  gemm_cvt<0, 6><<<576 + 10368, 256, 0, stream>>>(
      GA(xb, wqkg, bqkg, repb, nullptr, gtq, gtk, 0, 1344,
         1472, 768, 768, 768, 1344, 1.f, 1, 0, 0, 0, 0, 0, 0,
         mask, t_rope, 0, 12, 48, 1),
      576, rgat_w, rgatb, 10616832);
  // LPT: sc projections (480 blocks, long) first; gt-score (96, short) tail
  gemm_dual<0, 5, 1, 3><<<480 + 96, 256, 0, stream>>>(
      GA(repb, wq4g_scb, bscg, nullptr, nullptr, qb, nullptr, 0, 0,
         576, 672, 1344, 672, 576, 1.f, 2,
         0, 672, 0, 430080, 0, (long long)BS * 576,
         mask, t_rope, 576, 5, 48, 2),
      GA(gtq, gtk, nullptr, nullptr, plB, nullptr, nullptr, 8, 0,
         S, 64, 64, 64, 0, INV, 1,
         (long long)S * 64, 0, (long long)S * 64, 0, 0, 0,
         nullptr, nullptr, 0, 6, 1, B),
      480);
  // LPT: hr l=0 (2592 blocks, 24 K-steps) first; 9-head score (864, 2) tail
  gemm_dual<0, 2, 0, 8><<<2592 + 864, 256, 0, stream>>>(
      GA(xb, rgatb, nullptr, hr_t, nullptr, nullptr, nullptr, 0, 0,
         9 * H, H, H, H, S, 1.f, 1, 0, 0, 0, 0, (long long)9 * H * S, 0,
         nullptr, nullptr, 0, 54, 48, 1),
      GA(qb, kb, nullptr, scg_u, plB, nullptr, nullptr, 0, 0,
         S, 64, 576, 576, S, INV, 9,
         (long long)S * 576, 64, (long long)S * 576, 64,
         (long long)9 * S * S, (long long)S * S,
         nullptr, nullptr, 0, 6, 1, B * 9),
      2592);
  softmax_mask_kernel<<<B * 9 * S, 128, 0, stream>>>(scg_u, adjb);

  // ---- RGAT x2 (feat lives in inpb[:,768:1536]; x-copy fused in LN) ----
  adj_bmm_kernel<<<dim3(6, 3, B * 5), 256, 0, stream>>>(
      adjb, hr_t, Q0, Q1, Q2, Q3, Q4);
  ln_finalize_kernel<<<BS, 256, 0, stream>>>(Q0, Q1, Q2, Q3, Q4, xb, inpb);
  gemm_one<0, 2><<<dim3(54, 48, 1), 256, 0, stream>>>(GA(
      inpb + H, rgatb + (size_t)9 * H * H, nullptr, hr_t, nullptr, nullptr,
      nullptr, 0, 0,
      9 * H, H, 2 * H, H, S, 1.f, 1, 0, 0, 0, 0, (long long)9 * H * S, 0,
      nullptr, nullptr, 0, 54, 48, 1));
  adj_bmm_kernel<<<dim3(6, 3, B * 5), 256, 0, stream>>>(
      adjb, hr_t, Q0, Q1, Q2, Q3, Q4);
  ln_finalize_kernel<<<BS, 256, 0, stream>>>(Q0, Q1, Q2, Q3, Q4, xb, inpb);

  // ---- prediction head ----
  gemm_one<0, 6><<<dim3(16, 48, 1), 256, 0, stream>>>(GA(
      inpb, wqkp, bqkp, repb, nullptr, gtq, gtk, 0, 1920,
      2048, 1536, 1536, 1536, 1920, 1.f, 1, 0, 0, 0, 0, 0, 0,
      mask, t_rope, 0, 16, 48, 1));
  // LPT: pred sc projections (288, long) first; gt-score-p (96, short) tail
  gemm_dual<0, 5, 1, 3><<<288 + 96, 256, 0, stream>>>(
      GA(repb, wq_scb, bscp, nullptr, nullptr, qb, nullptr, 0, 0,
         384, 960, 1920, 960, 384, 1.f, 2,
         0, 960, 0, 368640, 0, (long long)BS * 384,
         mask, t_rope, 384, 3, 48, 2),
      GA(gtq, gtk, nullptr, nullptr, plA, nullptr, nullptr, 6, 0,
         S, 64, 64, 64, 0, INV, 1,
         (long long)S * 64, 0, (long long)S * 64, 0, 0, 0,
         nullptr, nullptr, 0, 6, 1, B),
      288);
  gemm_one<0, 3><<<dim3(6, 1, B * 6), 256, 0, stream>>>(GA(
      qb, qb + (size_t)BS * 384, nullptr, nullptr, plA, nullptr, nullptr, 0, 0,
      S, 64, 384, 384, 0, INV, 6,
      (long long)S * 384, 64, (long long)S * 384, 64, 0, 0,
      nullptr, nullptr, 0, 6, 1, B * 6));

  gather16_kernel<<<(int)((B * PAIRS + 255) / 256), 256, 0, stream>>>(plA, plB, out);
}

// Round 20
// 619.737 us; speedup vs baseline: 1.0198x; 1.0198x over previous
//
#include <hip/hip_runtime.h>
#include <math.h>

typedef unsigned short ushort_t;
typedef __attribute__((ext_vector_type(8))) short short8;
typedef __attribute__((ext_vector_type(4))) float f32x4;

// ---------------- problem constants ----------------
constexpr int B = 16, S = 384, H = 768;
constexpr int BS = B * S;                                // 6144
constexpr long long PAIRS = (long long)S * (S + 1) / 2;  // 73920
constexpr float INV = 0.125f;                            // 1/sqrt(64)

__device__ __forceinline__ ushort_t f2bf(float f) {
  unsigned int u = __float_as_uint(f);
  u += 0x7FFF + ((u >> 16) & 1);       // round-to-nearest-even
  return (ushort_t)(u >> 16);
}
__device__ __forceinline__ float bf2f(ushort_t u) {
  return __uint_as_float(((unsigned int)u) << 16);
}

__device__ __forceinline__ void glds16(const ushort_t* g, ushort_t* l) {
  __builtin_amdgcn_global_load_lds(
      (const __attribute__((address_space(1))) unsigned int*)g,
      (__attribute__((address_space(3))) unsigned int*)l, 16, 0, 0);
}

// ---------------- bulk fp32 -> bf16 convert + fused setup (rope/bias) ----------------
constexpr int NJOBS = 14;
struct CvtJobs {
  const float* src[NJOBS];
  ushort_t* dst[NJOBS];
  int n_real[NJOBS];
  int n_tot[NJOBS];
  int blk_off[NJOBS + 1];
};
__global__ __launch_bounds__(256) void cvt_setup_kernel(
    CvtJobs J, int cvtBlocks, float* tab,
    const float* g_repq, const float* g_repk, const float* g_gtq, const float* g_gtk,
    const float* p_repq, const float* p_repk, const float* p_gtq, const float* p_gtk,
    const float* g_scq, const float* g_sck, const float* p_scq, const float* p_sck,
    float* bqkg, float* bqkp, float* bscg, float* bscp) {
  int blk = blockIdx.x;
  if (blk >= cvtBlocks) {                 // fused setup region (56 blocks)
    int b = blk - cvtBlocks;
    if (b < 48) {
      int s = b * 8 + (threadIdx.x >> 5);
      int i = threadIdx.x & 31;
      double ang = (double)s / pow(10000.0, (double)i / 32.0);
      tab[s * 64 + 2 * i]     = (float)cos(ang);
      tab[s * 64 + 2 * i + 1] = (float)sin(ang);
    } else {
      int t = (b - 48) * 256 + threadIdx.x;
      if (t < 1472)
        bqkg[t] = t < 672 ? g_repq[t] : t < 1344 ? g_repk[t - 672]
                : t < 1408 ? g_gtq[t - 1344] : g_gtk[t - 1408];
      if (t < 2048)
        bqkp[t] = t < 960 ? p_repq[t] : t < 1920 ? p_repk[t - 960]
                : t < 1984 ? p_gtq[t - 1920] : p_gtk[t - 1984];
      if (t < 1152) bscg[t] = t < 576 ? g_scq[t] : g_sck[t - 576];
      if (t < 768)  bscp[t] = t < 384 ? p_scq[t] : p_sck[t - 384];
    }
    return;
  }
  int j = 0;
  while (j < NJOBS - 1 && blk >= J.blk_off[j + 1]) ++j;
  int i4 = (blk - J.blk_off[j]) * 256 + threadIdx.x;
  if (i4 * 4 >= J.n_tot[j]) return;
  ushort4 o;
  if (i4 * 4 < J.n_real[j]) {
    float4 v = ((const float4*)J.src[j])[i4];
    o = make_ushort4(f2bf(v.x), f2bf(v.y), f2bf(v.z), f2bf(v.w));
  } else {
    o = make_ushort4(0, 0, 0, 0);
  }
  ((ushort4*)J.dst[j])[i4] = o;
}

// ---------------- GEMM argument pack ----------------
struct GemmArgs {
  const ushort_t* A; const ushort_t* W; const float* bias; void* Cv;
  ushort_t* pl; ushort_t* qd; ushort_t* kd; int cbase, nsplit;
  int N, K, lda, ldw, ldc; float alpha; int nh;
  long long sAb, sAh, sWb, sWh, sCb, sCh;
  const float* mask; const float* tab; int biasN;
  int nx, ny, nz;
};

// ---------------- MFMA NT GEMM body, 2-phase pipelined ----------------
// CMODE semantics identical to prior rounds (2/3/5/6/8). XCD swizzle +
// GROUP_M=8 banding applied from the linear block id `flat`. SH: 17408 ushorts
// provided by the wrapper kernel (single allocation for dual dispatch).
template <int ACT, int CMODE>
__device__ void gemm_body(const GemmArgs g, int flat, ushort_t* SH) {
  const int nx = g.nx, ny = g.ny;
  int bx, by, bz;
  {
    const int nwg = nx * ny * g.nz;
    int l = (flat & 7) * (nwg >> 3) + (flat >> 3);
    const int pz = l / (nx * ny);
    int l2 = l - pz * (nx * ny);
    const int GM = 8;
    const int band = l2 / (GM * nx);
    const int rem = l2 - band * (GM * nx);
    const int gm = (ny - band * GM < GM) ? (ny - band * GM) : GM;
    bx = rem / gm;
    by = band * GM + (rem - bx * gm);
    bz = pz;
  }
  const int zb = bz / g.nh, zh = bz - zb * g.nh;
  const ushort_t* A = g.A + zb * g.sAb + zh * g.sAh;
  const ushort_t* W = g.W + zb * g.sWb + zh * g.sWh;
  const int t = threadIdx.x;
  int m0, n0;
  if (CMODE == 3 || CMODE == 8) {   // upper-pair map: bx in [0,6)
    const int ti = (bx < 3) ? 0 : (bx < 5 ? 1 : 2);
    const int tj = (bx < 3) ? bx : (bx < 5 ? bx - 2 : 2);
    m0 = ti * 128; n0 = tj * 128;
  } else {
    m0 = by * 128; n0 = bx * 128;
  }
  const int lane = t & 63, wid = t >> 6;
  const int wr = wid >> 1, wc = wid & 1;
  const int lrow = lane & 15, lk = lane >> 4;
  const int srow = t >> 2, sch = (t & 3) * 8;
  const int lda = g.lda, ldw = g.ldw, ldc = g.ldc;
  const ushort_t* Ag = A + (size_t)(m0 + srow) * lda + sch;
  const ushort_t* Wg = W + (size_t)(n0 + srow) * ldw + sch;
  const size_t a64 = (size_t)64 * lda, w64 = (size_t)64 * ldw;

  f32x4 acc[4][4];
#pragma unroll
  for (int i = 0; i < 4; ++i)
#pragma unroll
    for (int j = 0; j < 4; ++j) acc[i][j] = (f32x4){0.f, 0.f, 0.f, 0.f};

  auto stage = [&](int k0, int buf) {
    const int ao = buf * 4096, bo = 8192 + buf * 4096;
    glds16(Ag + k0, &SH[ao + t * 8]);
    glds16(Ag + k0 + a64, &SH[ao + 2048 + t * 8]);
    glds16(Wg + k0, &SH[bo + t * 8]);
    glds16(Wg + k0 + w64, &SH[bo + 2048 + t * 8]);
  };

  const int nk = g.K >> 5;
  stage(0, 0);
  for (int s = 0; s < nk; ++s) {
    __syncthreads();                       // stage(s) visible; prev reads done
    if (s + 1 < nk) stage((s + 1) << 5, (s + 1) & 1);
    const int ao = (s & 1) * 4096, bo = 8192 + (s & 1) * 4096;
    short8 av[4], bv[4];
#pragma unroll
    for (int i = 0; i < 4; ++i) {
      av[i] = *(const short8*)&SH[ao + (wr * 64 + i * 16 + lrow) * 32 + lk * 8];
      bv[i] = *(const short8*)&SH[bo + (wc * 64 + i * 16 + lrow) * 32 + lk * 8];
    }
#pragma unroll
    for (int i = 0; i < 4; ++i)
#pragma unroll
      for (int j = 0; j < 4; ++j)
        acc[i][j] = __builtin_amdgcn_mfma_f32_16x16x32_bf16(av[i], bv[j],
                                                            acc[i][j], 0, 0, 0);
  }

  if (CMODE == 2) {
    // LDS-staged transposed epilogue: tile [n_local][s_local], stride 136
    __syncthreads();
    const int bb = m0 / S;
    ushort_t* Cb = (ushort_t*)g.Cv + (size_t)bb * g.sCb;
    const int s_base = m0 - bb * S;
#pragma unroll
    for (int i = 0; i < 4; ++i) {
      const int sl = wr * 64 + i * 16 + lk * 4;
#pragma unroll
      for (int j = 0; j < 4; ++j) {
        const int nl = wc * 64 + j * 16 + lrow;
        ushort4 o = make_ushort4(f2bf(acc[i][j][0]), f2bf(acc[i][j][1]),
                                 f2bf(acc[i][j][2]), f2bf(acc[i][j][3]));
        *(ushort4*)&SH[nl * 136 + sl] = o;
      }
    }
    __syncthreads();
#pragma unroll
    for (int it = 0; it < 8; ++it) {
      const int row = it * 16 + wid * 4 + lk;
      ushort_t* dst = Cb + (size_t)(n0 + row) * ldc + s_base + lrow * 8;
      *(short8*)dst = *(const short8*)&SH[row * 136 + lrow * 8];
    }
  } else if (CMODE == 3) {
    ushort_t* plc = g.pl + ((size_t)(g.cbase + zh) * B + zb) * PAIRS;
#pragma unroll
    for (int j = 0; j < 4; ++j) {
      const int n = n0 + wc * 64 + j * 16 + lrow;
#pragma unroll
      for (int i = 0; i < 4; ++i) {
#pragma unroll
        for (int e = 0; e < 4; ++e) {
          const int m = m0 + wr * 64 + i * 16 + lk * 4 + e;
          if (n >= m) {
            long long p = (long long)m * S - (long long)m * (m - 1) / 2 + (n - m);
            float v = g.alpha * acc[i][j][e];
            if (ACT == 1) v = fmaxf(v, 0.f);
            plc[p] = f2bf(v);
          }
        }
      }
    }
  } else if (CMODE == 5) {
    // bias -> rope(pair via shfl_xor 1) -> mask -> bf16 to qd (+zh*sCh)
    ushort_t* Cq = g.qd + (size_t)zh * g.sCh;
    const float* bz2 = g.bias + (size_t)zh * g.biasN;
#pragma unroll
    for (int j = 0; j < 4; ++j) {
      const int n = n0 + wc * 64 + j * 16 + lrow;
      const float vb = (n < g.N) ? bz2[n] : 0.f;
      const int d = n & 63;
      const int ti2 = d & ~1;
#pragma unroll
      for (int i = 0; i < 4; ++i) {
#pragma unroll
        for (int e = 0; e < 4; ++e) {
          const int m = m0 + wr * 64 + i * 16 + lk * 4 + e;
          const int s = m % S;
          float v = (n < g.N) ? (acc[i][j][e] + vb) : 0.f;
          float pv = __shfl_xor(v, 1);
          float c = g.tab[s * 64 + ti2], sn = g.tab[s * 64 + ti2 + 1];
          float o = (d & 1) ? (v * c + pv * sn) : (v * c - pv * sn);
          o *= g.mask[m];
          if (n < g.N) Cq[(size_t)m * ldc + n] = f2bf(o);
        }
      }
    }
  } else if (CMODE == 6) {
    // split epilogue: rep (relu bf16) for n<nsplit, gt rope for nsplit<=n<N
    ushort_t* Cu = (ushort_t*)g.Cv;
#pragma unroll
    for (int j = 0; j < 4; ++j) {
      const int n = n0 + wc * 64 + j * 16 + lrow;
      const float vb = (n < g.N) ? g.bias[n] : 0.f;
#pragma unroll
      for (int i = 0; i < 4; ++i) {
#pragma unroll
        for (int e = 0; e < 4; ++e) {
          const int m = m0 + wr * 64 + i * 16 + lk * 4 + e;
          float v = (n < g.N) ? (acc[i][j][e] + vb) : 0.f;
          float pv = __shfl_xor(v, 1);
          if (n < g.nsplit) {
            Cu[(size_t)m * ldc + n] = f2bf(fmaxf(v, 0.f));
          } else if (n < g.N) {
            const int d = n - g.nsplit;
            const int dd = d & 63;
            const int ti2 = dd & ~1;
            const int s = m % S;
            float c = g.tab[s * 64 + ti2], sn = g.tab[s * 64 + ti2 + 1];
            float o = (dd & 1) ? (v * c + pv * sn) : (v * c - pv * sn);
            o *= g.mask[m];
            if (d < 64) g.qd[(size_t)m * 64 + dd] = f2bf(o);
            else        g.kd[(size_t)m * 64 + dd] = f2bf(o);
          }
        }
      }
    }
  } else if (CMODE == 8) {
    // symmetric score: att upper tile + planes, then LDS-mirrored tile
    ushort_t* Cu = (ushort_t*)g.Cv + zb * g.sCb + zh * g.sCh;
    ushort_t* plc = g.pl + ((size_t)(g.cbase + zh) * B + zb) * PAIRS;
    const bool diag = (m0 == n0);
#pragma unroll
    for (int j = 0; j < 4; ++j) {
      const int n = n0 + wc * 64 + j * 16 + lrow;
#pragma unroll
      for (int i = 0; i < 4; ++i) {
#pragma unroll
        for (int e = 0; e < 4; ++e) {
          const int m = m0 + wr * 64 + i * 16 + lk * 4 + e;
          float v = g.alpha * acc[i][j][e];
          ushort_t vb = f2bf(v);
          if (!diag || n >= m) Cu[(size_t)m * ldc + n] = vb;
          if (zh < 8 && n >= m) {
            long long p = (long long)m * S - (long long)m * (m - 1) / 2 + (n - m);
            plc[p] = vb;
          }
        }
      }
    }
    __syncthreads();   // all waves done reading SH (K-loop)
#pragma unroll
    for (int i = 0; i < 4; ++i) {
      const int sl = wr * 64 + i * 16 + lk * 4;
#pragma unroll
      for (int j = 0; j < 4; ++j) {
        const int nl = wc * 64 + j * 16 + lrow;
        ushort4 o4 = make_ushort4(f2bf(g.alpha * acc[i][j][0]),
                                  f2bf(g.alpha * acc[i][j][1]),
                                  f2bf(g.alpha * acc[i][j][2]),
                                  f2bf(g.alpha * acc[i][j][3]));
        *(ushort4*)&SH[nl * 136 + sl] = o4;
      }
    }
    __syncthreads();
#pragma unroll
    for (int it = 0; it < 8; ++it) {
      const int rowN = it * 16 + wid * 4 + lk;   // n-local 0..127
      const int colM = lrow * 8;                 // m-local chunk
      if (!diag) {
        *(short8*)&Cu[(size_t)(n0 + rowN) * ldc + m0 + colM] =
            *(const short8*)&SH[rowN * 136 + colM];
      } else {
#pragma unroll
        for (int q = 0; q < 8; ++q)
          if (rowN > colM + q)
            Cu[(size_t)(n0 + rowN) * ldc + m0 + colM + q] =
                SH[rowN * 136 + colM + q];
      }
    }
  }
}

template <int ACT, int CMODE>
__global__ __launch_bounds__(256) void gemm_one(GemmArgs g) {
  __shared__ __align__(16) ushort_t SH[17408];
  gemm_body<ACT, CMODE>(g, blockIdx.x + g.nx * (blockIdx.y + g.ny * blockIdx.z), SH);
}

// dual dispatch: two independent GEMM configs in one launch (1-D grid)
template <int ACTA, int CMA, int ACTB, int CMB>
__global__ __launch_bounds__(256) void gemm_dual(GemmArgs a, GemmArgs b, int nA) {
  __shared__ __align__(16) ushort_t SH[17408];
  int f = blockIdx.x;
  if (f < nA) gemm_body<ACTA, CMA>(a, f, SH);
  else        gemm_body<ACTB, CMB>(b, f - nA, SH);
}

// ---------------- adj bmm: Q[rg] = sum_{r in group} relu(adj[b,r] @ hr[b,r]) ----------------
// 5 relation groups (2,2,2,2,1) -> grid (6,3,B*5)=1440 blocks. bf16 partials.
__global__ __launch_bounds__(256) void adj_bmm_kernel(
    const ushort_t* __restrict__ adjb, const ushort_t* __restrict__ hrt,
    ushort_t* __restrict__ Q0, ushort_t* __restrict__ Q1,
    ushort_t* __restrict__ Q2, ushort_t* __restrict__ Q3,
    ushort_t* __restrict__ Q4) {
  __shared__ __align__(16) ushort_t As[2][128 * 32];
  __shared__ __align__(16) ushort_t Bs[2][128 * 32];
  int bx = blockIdx.x, by = blockIdx.y, bz = blockIdx.z;
  {   // XCD swizzle (nwg = 1440, %8==0)
    int nx = gridDim.x, ny = gridDim.y;
    int nwg = nx * ny * gridDim.z;
    int flat = bx + nx * (by + ny * bz);
    int l = (flat & 7) * (nwg >> 3) + (flat >> 3);
    bx = l % nx; l /= nx; by = l % ny; bz = l / ny;
  }
  const int b = bz / 5, rg = bz - b * 5;
  ushort_t* Q = (rg == 0) ? Q0 : (rg == 1) ? Q1 : (rg == 2) ? Q2
              : (rg == 3) ? Q3 : Q4;
  const int rel0 = (rg < 4) ? rg * 2 : 8;
  const int nsteps = (rg < 4) ? 24 : 12;   // 12 K-steps per relation
  const int t = threadIdx.x;
  const int m0 = by * 128, n0 = bx * 128;
  const int lane = t & 63, wid = t >> 6;
  const int wr = wid >> 1, wc = wid & 1;
  const int lrow = lane & 15, lk = lane >> 4;
  const int srow = t >> 2, sch = (t & 3) * 8;

  const ushort_t* adjA =
      adjb + ((size_t)(b * 9 + rel0) * S + m0 + srow) * S + sch;
  const ushort_t* hrA =
      hrt + ((size_t)(b * 9 + rel0) * H + n0 + srow) * S + sch;

  float mac[4][4][4];
#pragma unroll
  for (int i = 0; i < 4; ++i)
#pragma unroll
    for (int j = 0; j < 4; ++j)
#pragma unroll
      for (int e = 0; e < 4; ++e) mac[i][j][e] = 0.f;

  f32x4 acc[4][4];
#pragma unroll
  for (int i = 0; i < 4; ++i)
#pragma unroll
    for (int j = 0; j < 4; ++j) acc[i][j] = (f32x4){0.f, 0.f, 0.f, 0.f};

  auto stage = [&](int s, int buf) {
    const int rr = s / 12;
    const int k0 = (s - rr * 12) * 32;
    const ushort_t* Ag = adjA + (size_t)rr * S * S + k0;
    const ushort_t* Wg = hrA + (size_t)rr * H * S + k0;
    glds16(Ag, &As[buf][t * 8]);
    glds16(Ag + 64 * S, &As[buf][2048 + t * 8]);
    glds16(Wg, &Bs[buf][t * 8]);
    glds16(Wg + 64 * S, &Bs[buf][2048 + t * 8]);
  };

  stage(0, 0);
  for (int s = 0; s < nsteps; ++s) {
    __syncthreads();
    if (s + 1 < nsteps) stage(s + 1, (s + 1) & 1);
    const int buf = s & 1;
    short8 av[4], bv[4];
#pragma unroll
    for (int i = 0; i < 4; ++i) {
      av[i] = *(const short8*)&As[buf][(wr * 64 + i * 16 + lrow) * 32 + lk * 8];
      bv[i] = *(const short8*)&Bs[buf][(wc * 64 + i * 16 + lrow) * 32 + lk * 8];
    }
#pragma unroll
    for (int i = 0; i < 4; ++i)
#pragma unroll
      for (int j = 0; j < 4; ++j)
        acc[i][j] = __builtin_amdgcn_mfma_f32_16x16x32_bf16(av[i], bv[j],
                                                            acc[i][j], 0, 0, 0);
    if ((s % 12) == 11) {   // relation boundary: relu-accumulate, reset
#pragma unroll
      for (int i = 0; i < 4; ++i)
#pragma unroll
        for (int j = 0; j < 4; ++j) {
#pragma unroll
          for (int e = 0; e < 4; ++e)
            mac[i][j][e] += fmaxf(acc[i][j][e], 0.f);
          acc[i][j] = (f32x4){0.f, 0.f, 0.f, 0.f};
        }
    }
  }

#pragma unroll
  for (int i = 0; i < 4; ++i)
#pragma unroll
    for (int j = 0; j < 4; ++j)
#pragma unroll
      for (int e = 0; e < 4; ++e) {
        const int m = m0 + wr * 64 + i * 16 + lk * 4 + e;
        const int n = n0 + wc * 64 + j * 16 + lrow;
        Q[((size_t)b * S + m) * H + n] = f2bf(mac[i][j][e]);
      }
}

// ---------------- softmax row + (att!=0) mask: bf16 in -> bf16 adj ----------------
__global__ __launch_bounds__(128) void softmax_mask_kernel(
    const ushort_t* __restrict__ Mt, ushort_t* __restrict__ adjb) {
  __shared__ float red[128];
  int row = blockIdx.x;                // B*9*S rows
  const ushort_t* r = Mt + (size_t)row * S;
  ushort_t* o = adjb + (size_t)row * S;
  int t = threadIdx.x;
  const bool act = t < 96;             // 96 x ushort4 = 384 elems
  float v[4];
  float mx = -INFINITY;
  if (act) {
    ushort4 u = ((const ushort4*)r)[t];
    v[0] = bf2f(u.x); v[1] = bf2f(u.y); v[2] = bf2f(u.z); v[3] = bf2f(u.w);
    mx = fmaxf(fmaxf(v[0], v[1]), fmaxf(v[2], v[3]));
  }
  red[t] = mx; __syncthreads();
  for (int off2 = 64; off2 > 0; off2 >>= 1) {
    if (t < off2) red[t] = fmaxf(red[t], red[t + off2]);
    __syncthreads();
  }
  mx = red[0]; __syncthreads();
  float e4[4], s = 0.f;
  if (act) {
#pragma unroll
    for (int q = 0; q < 4; ++q) { e4[q] = expf(v[q] - mx); s += e4[q]; }
  }
  red[t] = s; __syncthreads();
  for (int off2 = 64; off2 > 0; off2 >>= 1) {
    if (t < off2) red[t] += red[t + off2];
    __syncthreads();
  }
  float invs = 1.f / red[0];
  if (act) {
    ushort4 ou;
    ou.x = f2bf((v[0] != 0.f) ? e4[0] * invs : 0.f);
    ou.y = f2bf((v[1] != 0.f) ? e4[1] * invs : 0.f);
    ou.z = f2bf((v[2] != 0.f) ? e4[2] * invs : 0.f);
    ou.w = f2bf((v[3] != 0.f) ? e4[3] * invs : 0.f);
    ((ushort4*)o)[t] = ou;
  }
}

// ---------------- RGAT finalize: feat = LN(sum(Q0..Q4)/9) -> bf16 into inp[:,768:1536],
// and copy xb -> inp[:,0:768] (fused). No partial aliases inp -> no hazard.
__global__ __launch_bounds__(256) void ln_finalize_kernel(
    const ushort_t* __restrict__ Q0, const ushort_t* __restrict__ Q1,
    const ushort_t* __restrict__ Q2, const ushort_t* __restrict__ Q3,
    const ushort_t* __restrict__ Q4, const ushort_t* __restrict__ xb,
    ushort_t* __restrict__ inp) {
  __shared__ float red[256];
  int row = blockIdx.x;
  const size_t base = (size_t)row * H;
  ushort_t* xrow = inp + (size_t)row * (2 * H);
  ushort_t* fb = xrow + H;
  int t = threadIdx.x;
  float v[3];
  float s = 0.f;
#pragma unroll
  for (int q = 0; q < 3; ++q) {
    size_t ix = base + t + q * 256;
    v[q] = (bf2f(Q0[ix]) + bf2f(Q1[ix]) + bf2f(Q2[ix]) + bf2f(Q3[ix]) +
            bf2f(Q4[ix])) / 9.0f;          // terms >= 0, relu is no-op
    s += v[q];
  }
  red[t] = s; __syncthreads();
#pragma unroll
  for (int q = 0; q < 3; ++q)
    xrow[t + q * 256] = xb[base + t + q * 256];
  for (int off2 = 128; off2 > 0; off2 >>= 1) {
    if (t < off2) red[t] += red[t + off2];
    __syncthreads();
  }
  float mean = red[0] / (float)H; __syncthreads();
  float s2 = 0.f;
#pragma unroll
  for (int q = 0; q < 3; ++q) { float d = v[q] - mean; s2 += d * d; }
  red[t] = s2; __syncthreads();
  for (int off2 = 128; off2 > 0; off2 >>= 1) {
    if (t < off2) red[t] += red[t + off2];
    __syncthreads();
  }
  float var = red[0] / (float)H;
  float rs = rsqrtf(var + 1e-5f);
#pragma unroll
  for (int q = 0; q < 3; ++q)
    fb[t + q * 256] = f2bf((v[q] - mean) * rs);
}

// ---------------- final gather: 16 bf16 planes -> out[b,p,16] fp32 ----------------
__global__ __launch_bounds__(256) void gather16_kernel(
    const ushort_t* __restrict__ plA, const ushort_t* __restrict__ plB,
    float* __restrict__ out) {
  int idx = blockIdx.x * 256 + threadIdx.x;          // b*PAIRS + p
  if (idx >= (int)(B * PAIRS)) return;
  const size_t PLN = (size_t)B * PAIRS;
  float v[16];
#pragma unroll
  for (int ch = 0; ch < 7; ++ch)  v[ch] = bf2f(plA[(size_t)ch * PLN + idx]);
#pragma unroll
  for (int ch = 7; ch < 16; ++ch) v[ch] = bf2f(plB[(size_t)(ch - 7) * PLN + idx]);
  float4* dst = (float4*)(out + (size_t)idx * 16);
#pragma unroll
  for (int q = 0; q < 4; ++q)
    dst[q] = make_float4(v[4 * q], v[4 * q + 1], v[4 * q + 2], v[4 * q + 3]);
}

// ---------------- launch ----------------
extern "C" void kernel_launch(void* const* d_in, const int* in_sizes, int n_in,
                              void* d_out, int out_size, void* d_ws, size_t ws_size,
                              hipStream_t stream) {
  (void)in_sizes; (void)n_in; (void)out_size; (void)ws_size;
  const float* x          = (const float*)d_in[0];
  const float* mask       = (const float*)d_in[1];
  const float* wq4gt_w    = (const float*)d_in[2];
  const float* wq4gt_b    = (const float*)d_in[3];
  const float* wk4gt_w    = (const float*)d_in[4];
  const float* wk4gt_b    = (const float*)d_in[5];
  const float* wq4g_rep_w = (const float*)d_in[6];
  const float* wq4g_rep_b = (const float*)d_in[7];
  const float* wq4g_sc_w  = (const float*)d_in[8];
  const float* wq4g_sc_b  = (const float*)d_in[9];
  const float* wk4g_rep_w = (const float*)d_in[10];
  const float* wk4g_rep_b = (const float*)d_in[11];
  const float* wk4g_sc_w  = (const float*)d_in[12];
  const float* wk4g_sc_b  = (const float*)d_in[13];
  const float* rgat_w     = (const float*)d_in[14];
  const float* wq4t_w     = (const float*)d_in[15];
  const float* wq4t_b     = (const float*)d_in[16];
  const float* wk4t_w     = (const float*)d_in[17];
  const float* wk4t_b     = (const float*)d_in[18];
  const float* wq_rep_w   = (const float*)d_in[19];
  const float* wq_rep_b   = (const float*)d_in[20];
  const float* wq_sc_w    = (const float*)d_in[21];
  const float* wq_sc_b    = (const float*)d_in[22];
  const float* wk_rep_w   = (const float*)d_in[23];
  const float* wk_rep_b   = (const float*)d_in[24];
  const float* wk_sc_w    = (const float*)d_in[25];
  const float* wk_sc_b    = (const float*)d_in[26];
  float* out = (float*)d_out;

  // ---- workspace carve-up (256B aligned); total ~267 MB ----
  char* wsb = (char*)d_ws;
  size_t off = 0;
  auto af = [&](size_t n) { float* p = (float*)(wsb + off);
                            off += ((n * 4 + 255) & ~(size_t)255); return p; };
  auto au = [&](size_t n) { ushort_t* p = (ushort_t*)(wsb + off);
                            off += ((n * 2 + 255) & ~(size_t)255); return p; };

  float* t_rope = af(24576);
  float* t_scg  = af((size_t)B * 9 * S * S);      // bf16 hr_t region
  float* t_acc  = af((size_t)BS * H);             // Q0+Q1 (bf16 partials)
  ushort_t* xb    = au((size_t)BS * H);
  ushort_t* inpb  = au((size_t)BS * 2 * H);       // scg_u head / [xb|feat] bf16
  ushort_t* repb  = au((size_t)BS * 1920);        // scg_u tail / Q2+Q3 / rep out
  ushort_t* qb    = au((size_t)BS * 576);         // kb must follow adjacently
  ushort_t* kb    = au((size_t)BS * 576);         // qb+kb host Q4 during RGAT
  ushort_t* adjb  = au((size_t)B * 9 * S * S);    // gtq/gtk carve pre-softmax
  ushort_t* plB   = au((size_t)9 * B * PAIRS);    // planes ch 7..15
  ushort_t* wqkg  = au(1179648);     // [1536,768]: repq|repk|gtq|gtk|pad
  ushort_t* wqkp  = au(3145728);     // [2048,1536]: repq|repk|gtq|gtk
  ushort_t* wq4g_scb = au(430080);   // [640,672] (576 real) -- adjacent pair
  ushort_t* wk4g_scb = au(430080);
  ushort_t* wq_scb   = au(368640);   // [384,960] -- adjacent pair
  ushort_t* wk_scb   = au(368640);
  ushort_t* rgatb    = au(10616832); // dead after last hr GEMM -> plA alias
  float* bqkg = af(1472);
  float* bqkp = af(2048);
  float* bscg = af(1152);
  float* bscp = af(768);

  // scg_u relocated to inpb+repb (exactly B*9*S*S ushorts, contiguous, both
  // dead in the score->softmax window) so score can run CONCURRENT with hr l=0.
  ushort_t* scg_u = inpb;
  ushort_t* hr_t  = (ushort_t*)t_scg;        // bf16 [B,9,H,S]
  ushort_t* plA   = rgatb;                   // planes ch 0..6 (16.6MB <= 21.2MB)
  ushort_t* gtq   = adjb;                    // gt q/k: adjb dead until softmax
  ushort_t* gtk   = adjb + (size_t)BS * 64;  // (graph) / dead after RGAT (pred)
  // bf16 RGAT partials (each BS*H ushorts = 9.44 MB), regions dead in RGAT:
  ushort_t* Q0 = (ushort_t*)t_acc;
  ushort_t* Q1 = Q0 + (size_t)BS * H;
  ushort_t* Q2 = repb;
  ushort_t* Q3 = Q2 + (size_t)BS * H;
  ushort_t* Q4 = qb;                         // qb+kb contiguous

  // ---- bulk convert weights (+x) to bf16 + fused setup ----
  {
    CvtJobs J;
    const float* srcs[NJOBS] = {wq4g_rep_w, wk4g_rep_w, wq4gt_w, wk4gt_w,
                                wq_rep_w, wk_rep_w, wq4t_w, wk4t_w,
                                wq4g_sc_w, wk4g_sc_w, wq_sc_w, wk_sc_w,
                                rgat_w, x};
    ushort_t* dsts[NJOBS] = {wqkg, wqkg + 516096, wqkg + 1032192, wqkg + 1081344,
                             wqkp, wqkp + 1474560, wqkp + 2949120, wqkp + 3047424,
                             wq4g_scb, wk4g_scb, wq_scb, wk_scb,
                             rgatb, xb};
    int nreal[NJOBS] = {516096, 516096, 49152, 49152,
                        1474560, 1474560, 98304, 98304,
                        387072, 387072, 368640, 368640,
                        10616832, 4718592};
    int ntot[NJOBS]  = {516096, 516096, 49152, 98304,
                        1474560, 1474560, 98304, 98304,
                        430080, 430080, 368640, 368640,
                        10616832, 4718592};
    int acc_blk = 0;
    for (int j = 0; j < NJOBS; ++j) {
      J.src[j] = srcs[j]; J.dst[j] = dsts[j];
      J.n_real[j] = nreal[j]; J.n_tot[j] = ntot[j];
      J.blk_off[j] = acc_blk;
      acc_blk += (ntot[j] + 1023) / 1024;
    }
    J.blk_off[NJOBS] = acc_blk;
    cvt_setup_kernel<<<acc_blk + 56, 256, 0, stream>>>(
        J, acc_blk, t_rope,
        wq4g_rep_b, wk4g_rep_b, wq4gt_b, wk4gt_b,
        wq_rep_b, wk_rep_b, wq4t_b, wk4t_b,
        wq4g_sc_b, wk4g_sc_b, wq_sc_b, wk_sc_b,
        bqkg, bqkp, bscg, bscp);
  }

  auto GA = [](const ushort_t* A, const ushort_t* W, const float* bias, void* Cv,
               ushort_t* pl, ushort_t* qd, ushort_t* kd, int cbase, int nsplit,
               int N, int K, int lda, int ldw, int ldc, float alpha, int nh,
               long long sAb, long long sAh, long long sWb, long long sWh,
               long long sCb, long long sCh,
               const float* mask, const float* tab, int biasN,
               int nx, int ny, int nz) {
    GemmArgs g{A, W, bias, Cv, pl, qd, kd, cbase, nsplit,
               N, K, lda, ldw, ldc, alpha, nh,
               sAb, sAh, sWb, sWh, sCb, sCh, mask, tab, biasN, nx, ny, nz};
    return g;
  };

  // ---- graph layer: merged rep-MLP + gt-proj (rope fused, split epilogue) ----
  gemm_one<0, 6><<<dim3(12, 48, 1), 256, 0, stream>>>(GA(
      xb, wqkg, bqkg, repb, nullptr, gtq, gtk, 0, 1344,
      1472, 768, 768, 768, 1344, 1.f, 1, 0, 0, 0, 0, 0, 0,
      mask, t_rope, 0, 12, 48, 1));
  // gt-score (ch15 plane, reads gtq/gtk) CONCURRENT with sc projections
  gemm_dual<1, 3, 0, 5><<<96 + 480, 256, 0, stream>>>(
      GA(gtq, gtk, nullptr, nullptr, plB, nullptr, nullptr, 8, 0,
         S, 64, 64, 64, 0, INV, 1,
         (long long)S * 64, 0, (long long)S * 64, 0, 0, 0,
         nullptr, nullptr, 0, 6, 1, B),
      GA(repb, wq4g_scb, bscg, nullptr, nullptr, qb, nullptr, 0, 0,
         576, 672, 1344, 672, 576, 1.f, 2,
         0, 672, 0, 430080, 0, (long long)BS * 576,
         mask, t_rope, 576, 5, 48, 2),
      96);
  // symmetric 9-head score (-> scg_u in inpb+repb) CONCURRENT with hr l=0
  gemm_dual<0, 8, 0, 2><<<864 + 2592, 256, 0, stream>>>(
      GA(qb, kb, nullptr, scg_u, plB, nullptr, nullptr, 0, 0,
         S, 64, 576, 576, S, INV, 9,
         (long long)S * 576, 64, (long long)S * 576, 64,
         (long long)9 * S * S, (long long)S * S,
         nullptr, nullptr, 0, 6, 1, B * 9),
      GA(xb, rgatb, nullptr, hr_t, nullptr, nullptr, nullptr, 0, 0,
         9 * H, H, H, H, S, 1.f, 1, 0, 0, 0, 0, (long long)9 * H * S, 0,
         nullptr, nullptr, 0, 54, 48, 1),
      864);
  softmax_mask_kernel<<<B * 9 * S, 128, 0, stream>>>(scg_u, adjb);

  // ---- RGAT x2 (feat lives in inpb[:,768:1536]; x-copy fused in LN) ----
  adj_bmm_kernel<<<dim3(6, 3, B * 5), 256, 0, stream>>>(
      adjb, hr_t, Q0, Q1, Q2, Q3, Q4);
  ln_finalize_kernel<<<BS, 256, 0, stream>>>(Q0, Q1, Q2, Q3, Q4, xb, inpb);
  gemm_one<0, 2><<<dim3(54, 48, 1), 256, 0, stream>>>(GA(
      inpb + H, rgatb + (size_t)9 * H * H, nullptr, hr_t, nullptr, nullptr,
      nullptr, 0, 0,
      9 * H, H, 2 * H, H, S, 1.f, 1, 0, 0, 0, 0, (long long)9 * H * S, 0,
      nullptr, nullptr, 0, 54, 48, 1));
  adj_bmm_kernel<<<dim3(6, 3, B * 5), 256, 0, stream>>>(
      adjb, hr_t, Q0, Q1, Q2, Q3, Q4);
  ln_finalize_kernel<<<BS, 256, 0, stream>>>(Q0, Q1, Q2, Q3, Q4, xb, inpb);

  // ---- prediction head ----
  gemm_one<0, 6><<<dim3(16, 48, 1), 256, 0, stream>>>(GA(
      inpb, wqkp, bqkp, repb, nullptr, gtq, gtk, 0, 1920,
      2048, 1536, 1536, 1536, 1920, 1.f, 1, 0, 0, 0, 0, 0, 0,
      mask, t_rope, 0, 16, 48, 1));
  // gt-score-p (ch6 plane) CONCURRENT with pred sc projections
  gemm_dual<1, 3, 0, 5><<<96 + 288, 256, 0, stream>>>(
      GA(gtq, gtk, nullptr, nullptr, plA, nullptr, nullptr, 6, 0,
         S, 64, 64, 64, 0, INV, 1,
         (long long)S * 64, 0, (long long)S * 64, 0, 0, 0,
         nullptr, nullptr, 0, 6, 1, B),
      GA(repb, wq_scb, bscp, nullptr, nullptr, qb, nullptr, 0, 0,
         384, 960, 1920, 960, 384, 1.f, 2,
         0, 960, 0, 368640, 0, (long long)BS * 384,
         mask, t_rope, 384, 3, 48, 2),
      96);
  gemm_one<0, 3><<<dim3(6, 1, B * 6), 256, 0, stream>>>(GA(
      qb, qb + (size_t)BS * 384, nullptr, nullptr, plA, nullptr, nullptr, 0, 0,
      S, 64, 384, 384, 0, INV, 6,
      (long long)S * 384, 64, (long long)S * 384, 64, 0, 0,
      nullptr, nullptr, 0, 6, 1, B * 6));

  gather16_kernel<<<(int)((B * PAIRS + 255) / 256), 256, 0, stream>>>(plA, plB, out);
}